// Round 4
// baseline (1079.077 us; speedup 1.0000x reference)
//
#include <hip/hip_runtime.h>
#include <hip/hip_bf16.h>

typedef __bf16 bf16_t;
typedef bf16_t bf16x8 __attribute__((ext_vector_type(8)));
typedef float  floatx4 __attribute__((ext_vector_type(4)));

constexpr int Bb = 4, Hh = 16, Nn = 2048, Dd = 64;
constexpr int BM = 128;  // queries per workgroup (8 waves)
constexpr int BN = 64;   // keys per tile
constexpr int WM = 16;   // queries per wave
constexpr int NT = Nn / BN;                          // 32 K/V tiles
constexpr float SCALE = 0.125f;                      // D^-0.5
constexpr float NEG   = -3.4028234663852886e38f;     // -FLT_MAX, matches reference

// Flash attention, bf16 MFMA (16x16x32), fp32 softmax state.
// Round-2 skeleton (single-buffer K/V, 2 barriers/tile) + softmax surgery:
//  - row-sum of P via an extra MFMA against a constant all-ones B-fragment
//    (sums the bf16-rounded P exactly; result broadcast to all lanes ->
//    the 16-bpermute sum reduce is GONE)
//  - per-quad group max instead of per-row max: online softmax is
//    self-normalizing, any upper bound works; 4 shfl_xor levels on ONE
//    scalar instead of 16 (mx/alpha collapse to scalars)
//  - bias+mask loaded (and mask folded: bb = ok ? bias : -FLT_MAX) BEFORE
//    the QK MFMAs so the VMEM latency hides under them;
//    fmaf(s, SCALE, -FLT_MAX) rounds to -FLT_MAX exactly.
__global__ __launch_bounds__(512, 4)
void attn_fwd(const float* __restrict__ qg,
              const float* __restrict__ kg,
              const float* __restrict__ vg,
              const void*  __restrict__ maskg,
              const float* __restrict__ biasg,
              float* __restrict__ outg)
{
    // chunk = ((blk*2+kk)*64 + quad*16 + n); element j <-> K[key=blk*16+n][d=kk*32+quad*8+j]
    __shared__ bf16x8 k_lds[512];
    // chunk = ((kk*4+nblk)*64 + quad*16 + n); element j <-> V[key=kk*32+quad*8+j][d=nblk*16+n]
    __shared__ bf16x8 v_lds[512];
    // per-wave P: chunk = kk*64 + quad*16 + m; element j <-> P[m][key=kk*32+quad*8+j]
    __shared__ bf16x8 p_lds[8][128];

    const int tid  = threadIdx.x;
    const int wave = tid >> 6;
    const int lane = tid & 63;
    const int ln   = lane & 15;   // n (or m) within 16
    const int lq   = lane >> 4;   // quad

    const int id = blockIdx.x;    // b fastest: 4 batches sharing a bias slice run adjacently
    const int b  = id & 3;
    const int h  = (id >> 2) & 15;
    const int mt = id >> 6;       // 0..15

    // ---- mask dtype probe (wave-uniform branch) ----
    const int probe = ((const int*)maskg)[lane];
    const bool mask_i32 = __all(probe == 0 || probe == 1);
    const int*           mi = (const int*)maskg;
    const unsigned char* mb = (const unsigned char*)maskg;

    const size_t head  = (size_t)(b*Hh + h) * Nn * Dd;
    const int    qbase = mt*BM + wave*WM;

    // ---- Q A-fragments straight from global (one-time) ----
    bf16x8 qa[2];
    {
        const float* qp = qg + head + (size_t)(qbase + ln)*Dd + lq*8;
        #pragma unroll
        for (int kk = 0; kk < 2; ++kk) {
            float4 f0 = *(const float4*)(qp + kk*32);
            float4 f1 = *(const float4*)(qp + kk*32 + 4);
            bf16x8 a;
            a[0]=(bf16_t)f0.x; a[1]=(bf16_t)f0.y; a[2]=(bf16_t)f0.z; a[3]=(bf16_t)f0.w;
            a[4]=(bf16_t)f1.x; a[5]=(bf16_t)f1.y; a[6]=(bf16_t)f1.z; a[7]=(bf16_t)f1.w;
            qa[kk] = a;
        }
    }

    // all-ones B-fragment for the row-sum MFMA
    bf16x8 ones;
    #pragma unroll
    for (int j = 0; j < 8; ++j) ones[j] = (bf16_t)1.0f;

    floatx4 o_acc[4];
    #pragma unroll
    for (int i = 0; i < 4; ++i) o_acc[i] = (floatx4){0.f,0.f,0.f,0.f};
    float mx = -__builtin_inff();
    float lsum[4];
    #pragma unroll
    for (int r = 0; r < 4; ++r) lsum[r] = 0.f;

    // staging decomposition (512 threads cover 64 keys x 64 d; 8 floats/thread each)
    const int skey = tid >> 3;
    const int sd0  = (tid & 7) * 8;
    const int sblk = skey >> 4, sn = skey & 15;          // K-side
    const int kkg  = sd0 >> 5,  qg2 = (sd0 >> 3) & 3;    // K chunk coords
    const int vkk  = skey >> 5, vq = (skey >> 3) & 3, vj = skey & 7;  // V-side
    const int vnb  = sd0 >> 4;                           // d-block constant per thread
    bf16_t* vl = (bf16_t*)v_lds;
    bf16_t* pl = (bf16_t*)p_lds[wave];

    for (int kt = 0; kt < NT; ++kt) {
        __syncthreads();   // previous tile's v_lds/k_lds reads complete
        {
            const float* kp = kg + head + (size_t)(kt*BN + skey)*Dd + sd0;
            const float* vp = vg + head + (size_t)(kt*BN + skey)*Dd + sd0;
            float4 k0 = *(const float4*)(kp);
            float4 k1 = *(const float4*)(kp + 4);
            float4 v0 = *(const float4*)(vp);
            float4 v1 = *(const float4*)(vp + 4);
            bf16x8 c;
            c[0]=(bf16_t)k0.x; c[1]=(bf16_t)k0.y; c[2]=(bf16_t)k0.z; c[3]=(bf16_t)k0.w;
            c[4]=(bf16_t)k1.x; c[5]=(bf16_t)k1.y; c[6]=(bf16_t)k1.z; c[7]=(bf16_t)k1.w;
            k_lds[(sblk*2 + kkg)*64 + qg2*16 + sn] = c;   // one b128 write
            float vvv[8];
            *(float4*)(vvv)   = v0;
            *(float4*)(vvv+4) = v1;
            #pragma unroll
            for (int t = 0; t < 8; ++t) {                 // V: transposed scatter (b16 writes)
                const int nn2 = (sd0 & 8) + t;            // (sd0+t) & 15
                vl[(((vkk*4 + vnb)*64 + vq*16 + nn2) << 3) | vj] = (bf16_t)vvv[t];
            }
        }
        __syncthreads();

        // ---- bias+mask first (VMEM latency hides under the QK MFMAs) ----
        float bb[4][4];
        {
            const size_t col0 = (size_t)kt*BN + ln;
            #pragma unroll
            for (int r = 0; r < 4; ++r) {
                const int m = qbase + lq*4 + r;
                const size_t brow = ((size_t)h*Nn + m)*Nn + col0;
                const size_t mrow = ((size_t)b*Nn + m)*Nn + col0;
                #pragma unroll
                for (int blk = 0; blk < 4; ++blk) {
                    const bool ok = mask_i32 ? (mi[mrow + blk*16] != 0)
                                             : (mb[mrow + blk*16] != 0);
                    bb[r][blk] = ok ? biasg[brow + blk*16] : NEG;
                }
            }
        }

        // ---- S = Q K^T  (16m x 64keys per wave) ----
        floatx4 s_acc[4];
        #pragma unroll
        for (int i = 0; i < 4; ++i) s_acc[i] = (floatx4){0.f,0.f,0.f,0.f};
        #pragma unroll
        for (int blk = 0; blk < 4; ++blk)
            #pragma unroll
            for (int kk = 0; kk < 2; ++kk)
                s_acc[blk] = __builtin_amdgcn_mfma_f32_16x16x32_bf16(
                    qa[kk], k_lds[(blk*2+kk)*64 + lane], s_acc[blk], 0, 0, 0);

        // ---- scale + bias(+mask folded); per-quad group max ----
        float gmax = NEG;
        #pragma unroll
        for (int r = 0; r < 4; ++r)
            #pragma unroll
            for (int blk = 0; blk < 4; ++blk) {
                // masked: fmaf(s, SCALE, -FLT_MAX) == -FLT_MAX exactly
                const float val = fmaf(s_acc[blk][r], SCALE, bb[r][blk]);
                s_acc[blk][r] = val;
                gmax = fmaxf(gmax, val);
            }
        #pragma unroll
        for (int off = 1; off < 16; off <<= 1)
            gmax = fmaxf(gmax, __shfl_xor(gmax, off, 64));

        const float mnew = fmaxf(mx, gmax);
        const float alph = __expf(mx - mnew);   // first tile: exp(-inf)=0
        mx = mnew;

        // ---- P = exp(S - mx) -> LDS (A-fragment layout) ----
        #pragma unroll
        for (int r = 0; r < 4; ++r) {
            const int m = lq*4 + r;
            #pragma unroll
            for (int blk = 0; blk < 4; ++blk) {
                const bf16_t p = (bf16_t)__expf(s_acc[blk][r] - mnew);
                const int key = blk*16 + ln;
                const int kk2 = key >> 5, q2 = (key >> 3) & 3, j2 = key & 7;
                pl[((kk2*64 + q2*16 + m) << 3) | j2] = p;
            }
        }
        #pragma unroll
        for (int r = 0; r < 4; ++r)
            #pragma unroll
            for (int nb = 0; nb < 4; ++nb)
                o_acc[nb][r] *= alph;

        // ---- O += P V ; row-sums via ones-MFMA (broadcast to all lanes) ----
        floatx4 sum_acc = (floatx4){0.f,0.f,0.f,0.f};
        #pragma unroll
        for (int kk = 0; kk < 2; ++kk) {
            const bf16x8 pa = p_lds[wave][kk*64 + lane];
            sum_acc = __builtin_amdgcn_mfma_f32_16x16x32_bf16(
                pa, ones, sum_acc, 0, 0, 0);
            #pragma unroll
            for (int nb = 0; nb < 4; ++nb)
                o_acc[nb] = __builtin_amdgcn_mfma_f32_16x16x32_bf16(
                    pa, v_lds[(kk*4+nb)*64 + lane], o_acc[nb], 0, 0, 0);
        }
        #pragma unroll
        for (int r = 0; r < 4; ++r)
            lsum[r] = lsum[r]*alph + sum_acc[r];
    }

    // ---- epilogue: O / l ----
    #pragma unroll
    for (int r = 0; r < 4; ++r) {
        const int m = qbase + lq*4 + r;
        const float inv = 1.f / lsum[r];
        float* op = outg + head + (size_t)m*Dd + ln;
        #pragma unroll
        for (int nb = 0; nb < 4; ++nb)
            op[nb*16] = o_acc[nb][r] * inv;
    }
}

extern "C" void kernel_launch(void* const* d_in, const int* in_sizes, int n_in,
                              void* d_out, int out_size, void* d_ws, size_t ws_size,
                              hipStream_t stream) {
    const float* q    = (const float*)d_in[0];
    const float* k    = (const float*)d_in[1];
    const float* v    = (const float*)d_in[2];
    const void*  mask = d_in[3];
    const float* bias = (const float*)d_in[4];
    float* out = (float*)d_out;
    (void)in_sizes; (void)n_in; (void)out_size; (void)d_ws; (void)ws_size;

    const int grid = Bb * Hh * (Nn / BM);   // 1024
    attn_fwd<<<grid, 512, 0, stream>>>(q, k, v, mask, bias, out);
}

// Round 5
// 901.892 us; speedup vs baseline: 1.1965x; 1.1965x over previous
//
#include <hip/hip_runtime.h>
#include <hip/hip_bf16.h>

typedef __bf16 bf16_t;
typedef bf16_t bf16x8 __attribute__((ext_vector_type(8)));
typedef float  floatx4 __attribute__((ext_vector_type(4)));

constexpr int Bb = 4, Hh = 16, Nn = 2048, Dd = 64;
constexpr int BM = 128;  // queries per workgroup (8 waves x 16)
constexpr int BN = 128;  // keys per tile (512B per bias-row visit)
constexpr int WM = 16;   // queries per wave
constexpr int NT = Nn / BN;                          // 16 K/V tiles
constexpr float SCALE = 0.125f;                      // D^-0.5
constexpr float NEG   = -3.4028234663852886e38f;     // -FLT_MAX, matches reference

// Flash attention, bf16 MFMA (16x16x32), fp32 softmax state.
// SWAPPED QK^T: S' = mfma(K_frag, Q_frag) = S[key][query].  The 16x16x32
// A/B fragment layouts are symmetric (m/n = lane&15, k = (lane>>4)*8+j), so
// the same LDS K-chunks and register Q-fragments serve as A and B directly.
// Payoff: each lane owns ONE query column ->
//   - bias/mask are loaded as per-lane float4/int4 (fully coalesced 64B
//     lines, 8+8 vector loads per wave-tile instead of 32 scalar loads)
//   - softmax max/sum are in-lane over 32 values + 2 shfl_xor (exact
//     per-query max), alpha/lsum are scalars
// BN=128 halves tiles/barriers and doubles the per-row-visit granule of the
// bias/mask streams (the kernel is pinned at ~1 TB/s effective HBM on those
// strided streams; bigger granules -> fewer DRAM row-activates per byte).
__global__ __launch_bounds__(512, 4)
void attn_fwd(const float* __restrict__ qg,
              const float* __restrict__ kg,
              const float* __restrict__ vg,
              const void*  __restrict__ maskg,
              const float* __restrict__ biasg,
              float* __restrict__ outg)
{
    // chunk = ((blk*2+kk)*64 + quad*16 + n); elem j <-> K[key=blk*16+n][d=kk*32+quad*8+j]
    __shared__ bf16x8 k_lds[1024];   // 8 key-blocks x 2 kk
    // chunk = ((kk*4+nblk)*64 + quad*16 + n); elem j <-> V[key=kk*32+quad*8+j][d=nblk*16+n]
    __shared__ bf16x8 v_lds[1024];   // kk = 0..3 (128 keys)
    // per-wave P (64-key half): chunk = kkh*64 + quad*16 + m; elem j <-> P[m][key=kkh*32+quad*8+j]
    __shared__ bf16x8 p_lds[8][128];

    const int tid  = threadIdx.x;
    const int wave = tid >> 6;
    const int lane = tid & 63;
    const int ln   = lane & 15;   // query within 16 (swapped C-layout column)
    const int lq   = lane >> 4;   // quad

    const int id = blockIdx.x;    // b fastest: 4 batches sharing a bias slice run adjacently
    const int b  = id & 3;
    const int h  = (id >> 2) & 15;
    const int mt = id >> 6;       // 0..15

    // ---- mask dtype probe (wave-uniform branch) ----
    const int probe = ((const int*)maskg)[lane];
    const bool mask_i32 = __all(probe == 0 || probe == 1);
    const int*           mi = (const int*)maskg;
    const unsigned char* mb = (const unsigned char*)maskg;

    const size_t head  = (size_t)(b*Hh + h) * Nn * Dd;
    const int    qbase = mt*BM + wave*WM;

    // ---- Q fragments straight from global (one-time); serve as MFMA B-operand ----
    bf16x8 qa[2];
    {
        const float* qp = qg + head + (size_t)(qbase + ln)*Dd + lq*8;
        #pragma unroll
        for (int kk = 0; kk < 2; ++kk) {
            float4 f0 = *(const float4*)(qp + kk*32);
            float4 f1 = *(const float4*)(qp + kk*32 + 4);
            bf16x8 a;
            a[0]=(bf16_t)f0.x; a[1]=(bf16_t)f0.y; a[2]=(bf16_t)f0.z; a[3]=(bf16_t)f0.w;
            a[4]=(bf16_t)f1.x; a[5]=(bf16_t)f1.y; a[6]=(bf16_t)f1.z; a[7]=(bf16_t)f1.w;
            qa[kk] = a;
        }
    }

    floatx4 o_acc[4];
    #pragma unroll
    for (int i = 0; i < 4; ++i) o_acc[i] = (floatx4){0.f,0.f,0.f,0.f};
    float mx = -__builtin_inff();   // running max of THIS lane's query
    float lsum = 0.f;               // running denom of THIS lane's query

    // staging decomposition (512 threads cover 128 keys x 64 d; 16 floats/thread each)
    const int skey = tid >> 2;                 // 0..127
    const int sd0  = (tid & 3) * 16;           // 0,16,32,48
    const int sblk = skey >> 4, sn = skey & 15;          // K-side
    const int vkk  = skey >> 5, vq = (skey >> 3) & 3, vj = skey & 7;  // V-side
    const int vnb  = sd0 >> 4;                 // d-block, constant per thread
    bf16_t* vl = (bf16_t*)v_lds;
    bf16_t* pl = (bf16_t*)p_lds[wave];

    // per-lane bias/mask row bases (row = this lane's query)
    const size_t brow0 = ((size_t)h*Nn + (qbase + ln))*Nn + lq*4;
    const size_t mrow0 = ((size_t)b*Nn + (qbase + ln))*Nn + lq*4;

    for (int kt = 0; kt < NT; ++kt) {
        __syncthreads();   // previous tile's v_lds/k_lds reads complete
        {
            const float* kp = kg + head + (size_t)(kt*BN + skey)*Dd + sd0;
            const float* vp = vg + head + (size_t)(kt*BN + skey)*Dd + sd0;
            float kvv[16], vvv[16];
            *(float4*)(kvv+ 0) = *(const float4*)(kp+ 0);
            *(float4*)(kvv+ 4) = *(const float4*)(kp+ 4);
            *(float4*)(kvv+ 8) = *(const float4*)(kp+ 8);
            *(float4*)(kvv+12) = *(const float4*)(kp+12);
            *(float4*)(vvv+ 0) = *(const float4*)(vp+ 0);
            *(float4*)(vvv+ 4) = *(const float4*)(vp+ 4);
            *(float4*)(vvv+ 8) = *(const float4*)(vp+ 8);
            *(float4*)(vvv+12) = *(const float4*)(vp+12);
            #pragma unroll
            for (int g = 0; g < 2; ++g) {             // K: two 16B chunk writes
                const int dg = sd0 + g*8;
                const int kkg = dg >> 5, qg2 = (dg >> 3) & 3;
                bf16x8 c;
                #pragma unroll
                for (int j = 0; j < 8; ++j) c[j] = (bf16_t)kvv[g*8+j];
                k_lds[(sblk*2 + kkg)*64 + qg2*16 + sn] = c;
            }
            #pragma unroll
            for (int t = 0; t < 16; ++t) {            // V: transposed scatter (b16 writes)
                vl[(((vkk*4 + vnb)*64 + vq*16 + t) << 3) | vj] = (bf16_t)vvv[t];
            }
        }
        __syncthreads();

        // ---- S' = K Q^T  (swapped: lane ln = query, rows = keys) ----
        floatx4 s_acc[8];
        #pragma unroll
        for (int i = 0; i < 8; ++i) s_acc[i] = (floatx4){0.f,0.f,0.f,0.f};
        #pragma unroll
        for (int blk = 0; blk < 8; ++blk)
            #pragma unroll
            for (int kk = 0; kk < 2; ++kk)
                s_acc[blk] = __builtin_amdgcn_mfma_f32_16x16x32_bf16(
                    k_lds[(blk*2+kk)*64 + lane], qa[kk], s_acc[blk], 0, 0, 0);
        // s_acc[blk][r] = S[key = blk*16 + lq*4 + r][query = qbase + ln]

        // ---- bias+mask: per-lane vector loads, fold into S ----
        {
            const size_t brow = brow0 + (size_t)kt*BN;
            const size_t mrow = mrow0 + (size_t)kt*BN;
            #pragma unroll
            for (int blk = 0; blk < 8; ++blk) {
                float4 b4 = *(const float4*)(biasg + brow + blk*16);
                float bfa[4] = {b4.x, b4.y, b4.z, b4.w};
                int oka[4];
                if (mask_i32) {
                    int4 m4 = *(const int4*)(mi + mrow + blk*16);
                    oka[0]=m4.x; oka[1]=m4.y; oka[2]=m4.z; oka[3]=m4.w;
                } else {
                    unsigned mu = *(const unsigned*)(mb + mrow + blk*16);
                    oka[0]=mu&255; oka[1]=(mu>>8)&255; oka[2]=(mu>>16)&255; oka[3]=(mu>>24)&255;
                }
                #pragma unroll
                for (int r = 0; r < 4; ++r) {
                    // masked: fmaf(s, SCALE, -FLT_MAX) == -FLT_MAX exactly
                    s_acc[blk][r] = fmaf(s_acc[blk][r], SCALE, oka[r] ? bfa[r] : NEG);
                }
            }
        }

        // ---- exact per-query max: in-lane over 32 + 2 shfl_xor across quads ----
        float m0 = NEG;
        #pragma unroll
        for (int blk = 0; blk < 8; ++blk) {
            const float a = fmaxf(fmaxf(s_acc[blk][0], s_acc[blk][1]),
                                  fmaxf(s_acc[blk][2], s_acc[blk][3]));
            m0 = fmaxf(m0, a);
        }
        m0 = fmaxf(m0, __shfl_xor(m0, 16, 64));
        m0 = fmaxf(m0, __shfl_xor(m0, 32, 64));
        const float mnew = fmaxf(mx, m0);
        const float alph = __expf(mx - mnew);   // first tile: exp(-inf)=0
        mx = mnew;

        // ---- P = exp(S - mx) (bf16-rounded, kept in regs) + row sum ----
        float rsum = 0.f;
        #pragma unroll
        for (int blk = 0; blk < 8; ++blk)
            #pragma unroll
            for (int r = 0; r < 4; ++r) {
                const float p = (float)(bf16_t)__expf(s_acc[blk][r] - mnew);
                s_acc[blk][r] = p;
                rsum += p;   // sum the bf16-rounded p: num/denom stay consistent
            }
        rsum += __shfl_xor(rsum, 16, 64);
        rsum += __shfl_xor(rsum, 32, 64);
        lsum = lsum*alph + rsum;

        // ---- rescale O (alpha redistributed to C-layout rows) ----
        #pragma unroll
        for (int r = 0; r < 4; ++r) {
            const float ar = __shfl(alph, lq*4 + r, 16);
            #pragma unroll
            for (int nb = 0; nb < 4; ++nb)
                o_acc[nb][r] *= ar;
        }

        // ---- P -> LDS (A-fragment layout) + O += P V, in two 64-key halves ----
        #pragma unroll
        for (int half = 0; half < 2; ++half) {
            #pragma unroll
            for (int blk = half*4; blk < half*4 + 4; ++blk)
                #pragma unroll
                for (int r = 0; r < 4; ++r) {
                    const int key = blk*16 + lq*4 + r;
                    pl[((((key>>5)&1)*64 + ((key>>3)&3)*16 + ln) << 3) | (key&7)]
                        = (bf16_t)s_acc[blk][r];
                }
            #pragma unroll
            for (int kk = half*2; kk < half*2 + 2; ++kk) {
                const bf16x8 pa = p_lds[wave][(kk&1)*64 + lane];
                #pragma unroll
                for (int nb = 0; nb < 4; ++nb)
                    o_acc[nb] = __builtin_amdgcn_mfma_f32_16x16x32_bf16(
                        pa, v_lds[(kk*4+nb)*64 + lane], o_acc[nb], 0, 0, 0);
            }
        }
    }

    // ---- epilogue: O / l (lsum redistributed like alpha) ----
    #pragma unroll
    for (int r = 0; r < 4; ++r) {
        const int m = qbase + lq*4 + r;
        const float inv = 1.f / __shfl(lsum, lq*4 + r, 16);
        float* op = outg + head + (size_t)m*Dd + ln;
        #pragma unroll
        for (int nb = 0; nb < 4; ++nb)
            op[nb*16] = o_acc[nb][r] * inv;
    }
}

extern "C" void kernel_launch(void* const* d_in, const int* in_sizes, int n_in,
                              void* d_out, int out_size, void* d_ws, size_t ws_size,
                              hipStream_t stream) {
    const float* q    = (const float*)d_in[0];
    const float* k    = (const float*)d_in[1];
    const float* v    = (const float*)d_in[2];
    const void*  mask = d_in[3];
    const float* bias = (const float*)d_in[4];
    float* out = (float*)d_out;
    (void)in_sizes; (void)n_in; (void)out_size; (void)d_ws; (void)ws_size;

    const int grid = Bb * Hh * (Nn / BM);   // 1024
    attn_fwd<<<grid, 512, 0, stream>>>(q, k, v, mask, bias, out);
}

// Round 6
// 867.460 us; speedup vs baseline: 1.2440x; 1.0397x over previous
//
#include <hip/hip_runtime.h>
#include <hip/hip_bf16.h>

typedef __bf16 bf16_t;
typedef bf16_t bf16x8 __attribute__((ext_vector_type(8)));
typedef float  floatx4 __attribute__((ext_vector_type(4)));

constexpr int Bb = 4, Hh = 16, Nn = 2048, Dd = 64;
constexpr int BM = 128;  // queries per workgroup (8 waves x 16)
constexpr int BN = 128;  // keys per tile (512B per bias-row visit)
constexpr int WM = 16;   // queries per wave
constexpr int NT = Nn / BN;                          // 16 K/V tiles
constexpr float SCALE = 0.125f;                      // D^-0.5
constexpr float NEG   = -3.4028234663852886e38f;     // -FLT_MAX, matches reference

// Flash attention, bf16 MFMA (16x16x32), fp32 softmax state.
// SWAPPED QK^T: S' = mfma(K_frag, Q_frag) = S[key][query]; each lane owns one
// query -> coalesced per-lane float4/int4 bias+mask loads, in-lane softmax.
// THIS ROUND: kill the register-allocator scratch spill. Round-5 counters
// showed WRITE_SIZE 391 MB (output is 33.5 MB) + FETCH inflated by ~360 MB:
// the allocator targeted 8 waves/EU (64-VGPR budget) and spilled the tile
// body to scratch to get occupancy that LDS/dispatch limits to 16 waves/CU
// anyway. amdgpu_waves_per_eu(2,4) caps the occupancy target at 4 waves/EU
// (= the 16 waves/CU we actually run), unlocking the 128-VGPR budget so the
// body fits spill-free.
__global__ __attribute__((amdgpu_flat_work_group_size(512, 512),
                          amdgpu_waves_per_eu(2, 4)))
void attn_fwd(const float* __restrict__ qg,
              const float* __restrict__ kg,
              const float* __restrict__ vg,
              const void*  __restrict__ maskg,
              const float* __restrict__ biasg,
              float* __restrict__ outg)
{
    // chunk = ((blk*2+kk)*64 + quad*16 + n); elem j <-> K[key=blk*16+n][d=kk*32+quad*8+j]
    __shared__ bf16x8 k_lds[1024];   // 8 key-blocks x 2 kk
    // chunk = ((kk*4+nblk)*64 + quad*16 + n); elem j <-> V[key=kk*32+quad*8+j][d=nblk*16+n]
    __shared__ bf16x8 v_lds[1024];   // kk = 0..3 (128 keys)
    // per-wave P (64-key half): chunk = kkh*64 + quad*16 + m; elem j <-> P[m][key=kkh*32+quad*8+j]
    __shared__ bf16x8 p_lds[8][128];

    const int tid  = threadIdx.x;
    const int wave = tid >> 6;
    const int lane = tid & 63;
    const int ln   = lane & 15;   // query within 16 (swapped C-layout column)
    const int lq   = lane >> 4;   // quad

    const int id = blockIdx.x;    // b fastest: 4 batches sharing a bias slice run adjacently
    const int b  = id & 3;
    const int h  = (id >> 2) & 15;
    const int mt = id >> 6;       // 0..15

    // ---- mask dtype probe (wave-uniform branch) ----
    const int probe = ((const int*)maskg)[lane];
    const bool mask_i32 = __all(probe == 0 || probe == 1);
    const int*           mi = (const int*)maskg;
    const unsigned char* mb = (const unsigned char*)maskg;

    const size_t head  = (size_t)(b*Hh + h) * Nn * Dd;
    const int    qbase = mt*BM + wave*WM;

    // ---- Q fragments straight from global (one-time); serve as MFMA B-operand ----
    bf16x8 qa[2];
    {
        const float* qp = qg + head + (size_t)(qbase + ln)*Dd + lq*8;
        #pragma unroll
        for (int kk = 0; kk < 2; ++kk) {
            float4 f0 = *(const float4*)(qp + kk*32);
            float4 f1 = *(const float4*)(qp + kk*32 + 4);
            bf16x8 a;
            a[0]=(bf16_t)f0.x; a[1]=(bf16_t)f0.y; a[2]=(bf16_t)f0.z; a[3]=(bf16_t)f0.w;
            a[4]=(bf16_t)f1.x; a[5]=(bf16_t)f1.y; a[6]=(bf16_t)f1.z; a[7]=(bf16_t)f1.w;
            qa[kk] = a;
        }
    }

    floatx4 o_acc[4];
    #pragma unroll
    for (int i = 0; i < 4; ++i) o_acc[i] = (floatx4){0.f,0.f,0.f,0.f};
    float mx = -__builtin_inff();   // running max of THIS lane's query
    float lsum = 0.f;               // running denom of THIS lane's query

    // staging decomposition (512 threads cover 128 keys x 64 d; 16 floats/thread each)
    const int skey = tid >> 2;                 // 0..127
    const int sd0  = (tid & 3) * 16;           // 0,16,32,48
    const int sblk = skey >> 4, sn = skey & 15;          // K-side
    const int vkk  = skey >> 5, vq = (skey >> 3) & 3, vj = skey & 7;  // V-side
    const int vnb  = sd0 >> 4;                 // d-block, constant per thread
    bf16_t* vl = (bf16_t*)v_lds;
    bf16_t* pl = (bf16_t*)p_lds[wave];

    // per-lane bias/mask row bases (row = this lane's query)
    const size_t brow0 = ((size_t)h*Nn + (qbase + ln))*Nn + lq*4;
    const size_t mrow0 = ((size_t)b*Nn + (qbase + ln))*Nn + lq*4;

    for (int kt = 0; kt < NT; ++kt) {
        __syncthreads();   // previous tile's v_lds/k_lds reads complete
        {
            const float* kp = kg + head + (size_t)(kt*BN + skey)*Dd + sd0;
            const float* vp = vg + head + (size_t)(kt*BN + skey)*Dd + sd0;
            float kvv[16], vvv[16];
            *(float4*)(kvv+ 0) = *(const float4*)(kp+ 0);
            *(float4*)(kvv+ 4) = *(const float4*)(kp+ 4);
            *(float4*)(kvv+ 8) = *(const float4*)(kp+ 8);
            *(float4*)(kvv+12) = *(const float4*)(kp+12);
            *(float4*)(vvv+ 0) = *(const float4*)(vp+ 0);
            *(float4*)(vvv+ 4) = *(const float4*)(vp+ 4);
            *(float4*)(vvv+ 8) = *(const float4*)(vp+ 8);
            *(float4*)(vvv+12) = *(const float4*)(vp+12);
            #pragma unroll
            for (int g = 0; g < 2; ++g) {             // K: two 16B chunk writes
                const int dg = sd0 + g*8;
                const int kkg = dg >> 5, qg2 = (dg >> 3) & 3;
                bf16x8 c;
                #pragma unroll
                for (int j = 0; j < 8; ++j) c[j] = (bf16_t)kvv[g*8+j];
                k_lds[(sblk*2 + kkg)*64 + qg2*16 + sn] = c;
            }
            #pragma unroll
            for (int t = 0; t < 16; ++t) {            // V: transposed scatter (b16 writes)
                vl[(((vkk*4 + vnb)*64 + vq*16 + t) << 3) | vj] = (bf16_t)vvv[t];
            }
        }
        __syncthreads();

        // ---- S' = K Q^T  (swapped: lane ln = query, rows = keys) ----
        floatx4 s_acc[8];
        #pragma unroll
        for (int i = 0; i < 8; ++i) s_acc[i] = (floatx4){0.f,0.f,0.f,0.f};
        #pragma unroll
        for (int blk = 0; blk < 8; ++blk)
            #pragma unroll
            for (int kk = 0; kk < 2; ++kk)
                s_acc[blk] = __builtin_amdgcn_mfma_f32_16x16x32_bf16(
                    k_lds[(blk*2+kk)*64 + lane], qa[kk], s_acc[blk], 0, 0, 0);
        // s_acc[blk][r] = S[key = blk*16 + lq*4 + r][query = qbase + ln]

        // ---- bias+mask: per-lane vector loads, fold into S ----
        {
            const size_t brow = brow0 + (size_t)kt*BN;
            const size_t mrow = mrow0 + (size_t)kt*BN;
            #pragma unroll
            for (int blk = 0; blk < 8; ++blk) {
                float4 b4 = *(const float4*)(biasg + brow + blk*16);
                float bfa[4] = {b4.x, b4.y, b4.z, b4.w};
                int oka[4];
                if (mask_i32) {
                    int4 m4 = *(const int4*)(mi + mrow + blk*16);
                    oka[0]=m4.x; oka[1]=m4.y; oka[2]=m4.z; oka[3]=m4.w;
                } else {
                    unsigned mu = *(const unsigned*)(mb + mrow + blk*16);
                    oka[0]=mu&255; oka[1]=(mu>>8)&255; oka[2]=(mu>>16)&255; oka[3]=(mu>>24)&255;
                }
                #pragma unroll
                for (int r = 0; r < 4; ++r) {
                    // masked: fmaf(s, SCALE, -FLT_MAX) == -FLT_MAX exactly
                    s_acc[blk][r] = fmaf(s_acc[blk][r], SCALE, oka[r] ? bfa[r] : NEG);
                }
            }
        }

        // ---- exact per-query max: in-lane over 32 + 2 shfl_xor across quads ----
        float m0 = NEG;
        #pragma unroll
        for (int blk = 0; blk < 8; ++blk) {
            const float a = fmaxf(fmaxf(s_acc[blk][0], s_acc[blk][1]),
                                  fmaxf(s_acc[blk][2], s_acc[blk][3]));
            m0 = fmaxf(m0, a);
        }
        m0 = fmaxf(m0, __shfl_xor(m0, 16, 64));
        m0 = fmaxf(m0, __shfl_xor(m0, 32, 64));
        const float mnew = fmaxf(mx, m0);
        const float alph = __expf(mx - mnew);   // first tile: exp(-inf)=0
        mx = mnew;

        // ---- P = exp(S - mx) (bf16-rounded, kept in regs) + row sum ----
        float rsum = 0.f;
        #pragma unroll
        for (int blk = 0; blk < 8; ++blk)
            #pragma unroll
            for (int r = 0; r < 4; ++r) {
                const float p = (float)(bf16_t)__expf(s_acc[blk][r] - mnew);
                s_acc[blk][r] = p;
                rsum += p;   // sum the bf16-rounded p: num/denom stay consistent
            }
        rsum += __shfl_xor(rsum, 16, 64);
        rsum += __shfl_xor(rsum, 32, 64);
        lsum = lsum*alph + rsum;

        // ---- rescale O (alpha redistributed to C-layout rows) ----
        #pragma unroll
        for (int r = 0; r < 4; ++r) {
            const float ar = __shfl(alph, lq*4 + r, 16);
            #pragma unroll
            for (int nb = 0; nb < 4; ++nb)
                o_acc[nb][r] *= ar;
        }

        // ---- P -> LDS (A-fragment layout) + O += P V, in two 64-key halves ----
        #pragma unroll
        for (int half = 0; half < 2; ++half) {
            #pragma unroll
            for (int blk = half*4; blk < half*4 + 4; ++blk)
                #pragma unroll
                for (int r = 0; r < 4; ++r) {
                    const int key = blk*16 + lq*4 + r;
                    pl[((((key>>5)&1)*64 + ((key>>3)&3)*16 + ln) << 3) | (key&7)]
                        = (bf16_t)s_acc[blk][r];
                }
            #pragma unroll
            for (int kk = half*2; kk < half*2 + 2; ++kk) {
                const bf16x8 pa = p_lds[wave][(kk&1)*64 + lane];
                #pragma unroll
                for (int nb = 0; nb < 4; ++nb)
                    o_acc[nb] = __builtin_amdgcn_mfma_f32_16x16x32_bf16(
                        pa, v_lds[(kk*4+nb)*64 + lane], o_acc[nb], 0, 0, 0);
            }
        }
    }

    // ---- epilogue: O / l (lsum redistributed like alpha) ----
    #pragma unroll
    for (int r = 0; r < 4; ++r) {
        const int m = qbase + lq*4 + r;
        const float inv = 1.f / __shfl(lsum, lq*4 + r, 16);
        float* op = outg + head + (size_t)m*Dd + ln;
        #pragma unroll
        for (int nb = 0; nb < 4; ++nb)
            op[nb*16] = o_acc[nb][r] * inv;
    }
}

extern "C" void kernel_launch(void* const* d_in, const int* in_sizes, int n_in,
                              void* d_out, int out_size, void* d_ws, size_t ws_size,
                              hipStream_t stream) {
    const float* q    = (const float*)d_in[0];
    const float* k    = (const float*)d_in[1];
    const float* v    = (const float*)d_in[2];
    const void*  mask = d_in[3];
    const float* bias = (const float*)d_in[4];
    float* out = (float*)d_out;
    (void)in_sizes; (void)n_in; (void)out_size; (void)d_ws; (void)ws_size;

    const int grid = Bb * Hh * (Nn / BM);   // 1024
    attn_fwd<<<grid, 512, 0, stream>>>(q, k, v, mask, bias, out);
}